// Round 18
// baseline (95.217 us; speedup 1.0000x reference)
//
#include <hip/hip_runtime.h>
#include <hip/hip_bf16.h>
#include <cstdint>

// STFT magnitude via real-packed radix-4 FFT (round 18 = r17, tst -> global).
// r17's fft kernel was capped by LDS allocation: 40,960B = exactly 4 blocks/CU.
// The 8KB tst table moves to global reads (L1-resident; stage-4/6 = 16-line
// broadcast gathers, stage-8 = lane-coalesced) -> LDS 32,768B = 5 blocks/CU
// (62.5% theoretical occupancy) and the kernel is now completely BARRIER-FREE.
// r11 tried global twiddles and lost -- but via per-q barrier convoys + VGPR
// 148 at 2 blocks/CU; neither mechanism exists in this structure (no barriers,
// VGPR 60, occupancy-limited per r16->r17 evidence).
// Everything else byte-identical to r17 (direct f32 reads w/ wave-uniform
// reflect branch, stages 0+2 and 4+6 in registers, r9-proven transpose).

#define FILT   2048
#define HOP    512
#define CUT    1025
#define NBATCH 32
#define TFR    626
#define NFR    (NBATCH * TFR)      // 20032
#define LSIG   320000
#define N2     1024                // complex FFT length
#define MWS    1088                // mag_ws row stride (bf16), 128B-aligned
#define KT     17                  // k-tiles (ceil 1025/64)
#define TT     20                  // t-tiles (ceil 626/32)

typedef __attribute__((ext_vector_type(8))) short short8;

__device__ __forceinline__ short bf16r(float f) {
  __hip_bfloat16 h = __float2bfloat16(f);
  return __builtin_bit_cast(short, h);
}
__device__ __forceinline__ float bf2f(uint32_t u) {
  return __builtin_bit_cast(float, u << 16);
}

__device__ __forceinline__ short8 pack8(float4 a, float4 b) {
  short8 v;
  v[0] = bf16r(a.x); v[1] = bf16r(a.y); v[2] = bf16r(a.z); v[3] = bf16r(a.w);
  v[4] = bf16r(b.x); v[5] = bf16r(b.y); v[6] = bf16r(b.z); v[7] = bf16r(b.w);
  return v;
}

// -------- stage 1: twiddle + hann tables --------
__global__ void make_tables(float* __restrict__ hann, float2* __restrict__ Tst,
                            float2* __restrict__ Tun) {
  const int i = blockIdx.x * 256 + threadIdx.x;    // 0..2047
  const float PI2 = 6.283185307179586f;
  if (i < 2048) hann[i] = 0.5f - 0.5f * cosf(PI2 * (float)i / 2048.0f);
  if (i < 1024) {
    float s, c;
    sincosf(-PI2 * (float)i / 1024.0f, &s, &c);
    Tst[i] = make_float2(c, s);                    // W_1024^i (forward)
    sincosf(-PI2 * (float)i / 2048.0f, &s, &c);
    Tun[i] = make_float2(c, s);                    // W_2048^i (unpack)
  }
}

__device__ __forceinline__ float2 cmul(float2 a, float2 b) {
  return make_float2(a.x * b.x - a.y * b.y, a.x * b.y + a.y * b.x);
}
__device__ __forceinline__ float2 cmulc(float2 a, float cx, float cy) {
  return make_float2(a.x * cx - a.y * cy, a.x * cy + a.y * cx);
}

__device__ __forceinline__ int SW(int i) { return i ^ ((i >> 4) & 15); }

// natural-order 16-pt DFT in registers (r10/r14/r15-verified); literal twiddles
__device__ __forceinline__ void fft16(float2* y) {
  static constexpr float TX[4][4] = {
    {1.f, 1.f, 1.f, 1.f},
    {1.f,  0.92387953251128674f,  0.70710678118654752f,  0.38268343236508978f},
    {1.f,  0.70710678118654752f,  0.f,                  -0.70710678118654752f},
    {1.f,  0.38268343236508978f, -0.70710678118654752f, -0.92387953251128674f}};
  static constexpr float TY[4][4] = {
    {0.f, 0.f, 0.f, 0.f},
    {0.f, -0.38268343236508978f, -0.70710678118654752f, -0.92387953251128674f},
    {0.f, -0.70710678118654752f, -1.f,                  -0.70710678118654752f},
    {0.f, -0.92387953251128674f, -0.70710678118654752f,  0.38268343236508978f}};
  float2 G[16];
  #pragma unroll
  for (int n0 = 0; n0 < 4; ++n0) {
    float2 a0 = y[n0], a1 = y[n0 + 4], a2 = y[n0 + 8], a3 = y[n0 + 12];
    float2 e = make_float2(a0.x + a2.x, a0.y + a2.y);
    float2 f = make_float2(a0.x - a2.x, a0.y - a2.y);
    float2 g = make_float2(a1.x + a3.x, a1.y + a3.y);
    float2 h = make_float2(a1.x - a3.x, a1.y - a3.y);
    float2 F0 = make_float2(e.x + g.x, e.y + g.y);
    float2 F1 = make_float2(f.x + h.y, f.y - h.x);   // f - i*h
    float2 F2 = make_float2(e.x - g.x, e.y - g.y);
    float2 F3 = make_float2(f.x - h.y, f.y + h.x);   // f + i*h
    G[n0 * 4 + 0] = F0;
    G[n0 * 4 + 1] = cmulc(F1, TX[n0][1], TY[n0][1]);
    G[n0 * 4 + 2] = cmulc(F2, TX[n0][2], TY[n0][2]);
    G[n0 * 4 + 3] = cmulc(F3, TX[n0][3], TY[n0][3]);
  }
  #pragma unroll
  for (int q = 0; q < 4; ++q) {
    float2 a0 = G[q], a1 = G[4 + q], a2 = G[8 + q], a3 = G[12 + q];
    float2 e = make_float2(a0.x + a2.x, a0.y + a2.y);
    float2 f = make_float2(a0.x - a2.x, a0.y - a2.y);
    float2 g = make_float2(a1.x + a3.x, a1.y + a3.y);
    float2 h = make_float2(a1.x - a3.x, a1.y - a3.y);
    y[q]      = make_float2(e.x + g.x, e.y + g.y);
    y[q + 4]  = make_float2(f.x + h.y, f.y - h.x);
    y[q + 8]  = make_float2(e.x - g.x, e.y - g.y);
    y[q + 12] = make_float2(f.x - h.y, f.y + h.x);
  }
}

// radix-4 DIT stage (r8-proven); tw may be a GLOBAL pointer (L1-hot table)
template<int LOG>
__device__ __forceinline__ void fft_stage(float2* z, const float2* __restrict__ tw,
                                          int lane) {
  constexpr int M4 = 1 << LOG;
  constexpr int STRIDE = 1 << (8 - LOG);
  #pragma unroll
  for (int u = 0; u < 4; ++u) {
    const int bf = u * 64 + lane;
    const int j  = bf & (M4 - 1);
    const int i0 = ((bf >> LOG) << (LOG + 2)) | j;
    const int i1 = i0 + M4, i2 = i0 + 2 * M4, i3 = i0 + 3 * M4;
    const int p0 = SW(i0), p1 = SW(i1), p2 = SW(i2), p3 = SW(i3);
    float2 a = z[p0], b = z[p1], c = z[p2], d = z[p3];
    if (LOG > 0) {
      b = cmul(b, tw[j * STRIDE]);
      c = cmul(c, tw[2 * j * STRIDE]);
      d = cmul(d, tw[3 * j * STRIDE]);
    }
    const float2 t0 = make_float2(a.x + c.x, a.y + c.y);
    const float2 t1 = make_float2(a.x - c.x, a.y - c.y);
    const float2 t2 = make_float2(b.x + d.x, b.y + d.y);
    const float2 t3 = make_float2(b.x - d.x, b.y - d.y);
    z[p0] = make_float2(t0.x + t2.x, t0.y + t2.y);
    z[p1] = make_float2(t1.x + t3.y, t1.y - t3.x);   // t1 - i*t3
    z[p2] = make_float2(t0.x - t2.x, t0.y - t2.y);
    z[p3] = make_float2(t1.x - t3.y, t1.y + t3.x);   // t1 + i*t3
  }
}

// -------- stage 2: windowed rFFT magnitude -> bf16 MW[f][k] coalesced --------
__global__ __launch_bounds__(256)
void stft_fft(const float* __restrict__ x, const float* __restrict__ hann,
              const float2* __restrict__ Tst, const float2* __restrict__ Tun,
              ushort* __restrict__ MW)
{
  __shared__ float2 zsh[4][1024];    // per-wave z, XOR-swizzled; 32768 B total
                                     // (5 blocks/CU; NO other LDS, NO barriers)

  const int tid = threadIdx.x, wv = tid >> 6, lane = tid & 63;
  float2* z = zsh[wv];

  // per-lane geometry
  const int G  = ((lane & 3) << 4) | (lane & 12) | (lane >> 4);  // base-4 reverse
  const int zb = 16 * G, gm = G & 15;
  const int j0 = lane & 15, B = lane >> 4;

  const int f = blockIdx.x * 4 + wv;              // 1 frame per wave, grid NFR/4
  const int b = f / TFR, t = f - b * TFR;
  const float* xb = x + (size_t)b * LSIG;
  const int off = t * HOP - 1024;

  // load f32 pairs directly, window, stages 0+2 in registers, scatter
  float2 y[16];
  if (t >= 2 && t <= 623) {                       // interior: off>=0, off+2047<LSIG
    #pragma unroll
    for (int u = 0; u < 16; ++u) {
      const int n = u * 64 + lane;
      const float2 p = *(const float2*)(xb + off + 2 * n);
      const float2 h = *(const float2*)(hann + 2 * n);
      y[u] = make_float2(p.x * h.x, p.y * h.y);
    }
  } else {                                        // boundary: per-element reflect
    #pragma unroll
    for (int u = 0; u < 16; ++u) {
      const int n = u * 64 + lane;
      int ja = off + 2 * n, jb = ja + 1;
      ja = ja < 0 ? -ja : (ja >= LSIG ? 2 * LSIG - 2 - ja : ja);
      jb = jb < 0 ? -jb : (jb >= LSIG ? 2 * LSIG - 2 - jb : jb);
      const float2 h = *(const float2*)(hann + 2 * n);
      y[u] = make_float2(xb[ja] * h.x, xb[jb] * h.y);
    }
  }
  fft16(y);
  #pragma unroll
  for (int k = 0; k < 16; ++k) z[zb + (k ^ gm)] = y[k];

  // stages 4+6 in registers on closed set {j0 + 16a + 64b2 + 256B} (r14 math)
  {
    float2 g[4][4];
    #pragma unroll
    for (int a = 0; a < 4; ++a)
      #pragma unroll
      for (int b2 = 0; b2 < 4; ++b2)
        g[a][b2] = z[16 * (a + 4 * b2 + 16 * B) + (j0 ^ (a + 4 * b2))];
    // stage 4 (over a): STRIDE=16 -> twiddles Tst[16*j0 * {1,2,3}] (global, L1)
    const float2 w41 = Tst[16 * j0], w42 = Tst[32 * j0], w43 = Tst[48 * j0];
    #pragma unroll
    for (int b2 = 0; b2 < 4; ++b2) {
      float2 a0 = g[0][b2];
      float2 a1 = cmul(g[1][b2], w41);
      float2 a2 = cmul(g[2][b2], w42);
      float2 a3 = cmul(g[3][b2], w43);
      const float2 t0 = make_float2(a0.x + a2.x, a0.y + a2.y);
      const float2 t1 = make_float2(a0.x - a2.x, a0.y - a2.y);
      const float2 t2 = make_float2(a1.x + a3.x, a1.y + a3.y);
      const float2 t3 = make_float2(a1.x - a3.x, a1.y - a3.y);
      g[0][b2] = make_float2(t0.x + t2.x, t0.y + t2.y);
      g[1][b2] = make_float2(t1.x + t3.y, t1.y - t3.x);
      g[2][b2] = make_float2(t0.x - t2.x, t0.y - t2.y);
      g[3][b2] = make_float2(t1.x - t3.y, t1.y + t3.x);
    }
    // stage 6 (over b2): STRIDE=4 -> twiddles Tst[4*(j0+16*mp) * {1,2,3}]
    #pragma unroll
    for (int mp = 0; mp < 4; ++mp) {
      const int jj = 4 * (j0 + 16 * mp);
      float2 a0 = g[mp][0];
      float2 a1 = cmul(g[mp][1], Tst[jj]);
      float2 a2 = cmul(g[mp][2], Tst[2 * jj]);
      float2 a3 = cmul(g[mp][3], Tst[3 * jj]);
      const float2 t0 = make_float2(a0.x + a2.x, a0.y + a2.y);
      const float2 t1 = make_float2(a0.x - a2.x, a0.y - a2.y);
      const float2 t2 = make_float2(a1.x + a3.x, a1.y + a3.y);
      const float2 t3 = make_float2(a1.x - a3.x, a1.y - a3.y);
      g[mp][0] = make_float2(t0.x + t2.x, t0.y + t2.y);
      g[mp][1] = make_float2(t1.x + t3.y, t1.y - t3.x);
      g[mp][2] = make_float2(t0.x - t2.x, t0.y - t2.y);
      g[mp][3] = make_float2(t1.x - t3.y, t1.y + t3.x);
    }
    #pragma unroll
    for (int mp = 0; mp < 4; ++mp)
      #pragma unroll
      for (int m2 = 0; m2 < 4; ++m2)
        z[16 * (mp + 4 * m2 + 16 * B) + (j0 ^ (mp + 4 * m2))] = g[mp][m2];
  }

  fft_stage<8>(z, Tst, lane);        // twiddles from global (lane-coalesced)

  // mirror-pair unpack -> bf16 MW[f][*] (both directions coalesced)
  ushort* mw = MW + (size_t)f * MWS;
  #pragma unroll
  for (int v = 0; v < 8; ++v) {
    const int k = v * 64 + lane;                     // 0..511
    const float2 Zk = z[SW(k)];
    const int km = (N2 - k) & (N2 - 1);
    const float2 Zm = z[SW(km)];
    const float xer = 0.5f * (Zk.x + Zm.x);
    const float xei = 0.5f * (Zk.y - Zm.y);
    const float xor_ = 0.5f * (Zk.y + Zm.y);
    const float xoi = -0.5f * (Zk.x - Zm.x);
    const float2 w = Tun[k];                         // global, coalesced, L1-hot
    const float px = w.x * xor_ - w.y * xoi;
    const float py = w.x * xoi + w.y * xor_;
    const float Xr = xer + px, Xi = xei + py;
    const float Yr = xer - px, Yi = xei - py;
    mw[k]        = (ushort)bf16r(sqrtf(Xr * Xr + Xi * Xi));
    mw[1024 - k] = (ushort)bf16r(sqrtf(Yr * Yr + Yi * Yi));
  }
  if (lane == 0) {                                   // k=512 self-paired
    const float2 Zc = z[SW(512)];
    mw[512] = (ushort)bf16r(sqrtf(Zc.x * Zc.x + Zc.y * Zc.y));
  }
}

// -------- stage 3: transpose [f][k] bf16 -> out[b][k][t] f32 (r9-proven) --------
__global__ __launch_bounds__(256)
void transpose_out(const ushort* __restrict__ MW, float* __restrict__ out) {
  __shared__ float tile[64][33];
  const int b  = blockIdx.y;
  const int kt = blockIdx.x % KT;
  const int tt = blockIdx.x / KT;
  const int k0 = kt * 64, t0 = tt * 32;
  const int tid = threadIdx.x;
  const int r = tid >> 5, c = tid & 31;

  #pragma unroll
  for (int s = 0; s < 4; ++s) {
    const int t = t0 + r + 8 * s;
    if (t < TFR) {
      const uint32_t pr =
        *(const uint32_t*)(MW + (size_t)(b * TFR + t) * MWS + k0 + 2 * c);
      tile[2 * c][r + 8 * s]     = bf2f(pr & 0xffffu);
      tile[2 * c + 1][r + 8 * s] = bf2f(pr >> 16);
    }
  }
  __syncthreads();

  const int kk = tid >> 2, toff = (tid & 3) * 8;
  const int k = k0 + kk;
  if (k < CUT) {
    float* pptr = out + (size_t)b * (CUT * TFR) + (size_t)k * TFR + t0 + toff;
    if (t0 + 32 <= TFR) {
      float4 v0 = make_float4(tile[kk][toff], tile[kk][toff + 1],
                              tile[kk][toff + 2], tile[kk][toff + 3]);
      float4 v1 = make_float4(tile[kk][toff + 4], tile[kk][toff + 5],
                              tile[kk][toff + 6], tile[kk][toff + 7]);
      *(float4*)pptr = v0;
      *(float4*)(pptr + 4) = v1;
    } else {
      #pragma unroll
      for (int e = 0; e < 8; ++e) {
        const int t = t0 + toff + e;
        if (t < TFR) pptr[e] = tile[kk][toff + e];
      }
    }
  }
}

// -------- fallback: reg-staged 128x128 MFMA GEMM (no ws needed) --------
typedef __attribute__((ext_vector_type(4))) float f32x4;

__global__ __launch_bounds__(256, 2)
void stft_gemm_fb(const float* __restrict__ basis, const float* __restrict__ x,
                  float* __restrict__ out)
{
  __shared__ alignas(16) short sA[2][128][64];
  __shared__ alignas(16) short sB[128][64];

  const int tid  = threadIdx.x;
  const int wave = tid >> 6;
  const int lane = tid & 63;
  const int n0 = blockIdx.x * 128;
  const int m0 = blockIdx.y * 128;

  f32x4 acc_r[4][4], acc_i[4][4];
  #pragma unroll
  for (int i = 0; i < 4; ++i)
    #pragma unroll
    for (int j = 0; j < 4; ++j) { acc_r[i][j] = (f32x4)0.f; acc_i[i][j] = (f32x4)0.f; }

  const int sr = tid >> 1;
  const int sh = (tid & 1) * 32;

  for (int k0 = 0; k0 < FILT; k0 += 64) {
    #pragma unroll
    for (int p = 0; p < 2; ++p) {
      const int k = m0 + sr;
      short8 v[4];
      if (k < CUT) {
        const float* src = basis + (size_t)(p * CUT + k) * FILT + k0 + sh;
        #pragma unroll
        for (int qq = 0; qq < 4; ++qq) {
          float4 a = *(const float4*)(src + qq * 8);
          float4 b = *(const float4*)(src + qq * 8 + 4);
          v[qq] = pack8(a, b);
        }
      } else {
        #pragma unroll
        for (int qq = 0; qq < 4; ++qq) v[qq] = (short8)(short)0;
      }
      #pragma unroll
      for (int qq = 0; qq < 4; ++qq) *(short8*)&sA[p][sr][sh + qq * 8] = v[qq];
    }
    {
      const int f = n0 + sr;
      short8 v[4];
      if (f < NFR) {
        const int b = f / TFR, t = f - b * TFR;
        const float* xb = x + (size_t)b * LSIG;
        const int j0 = t * HOP + k0 + sh - 1024;
        if (j0 >= 0 && j0 + 32 <= LSIG) {
          #pragma unroll
          for (int qq = 0; qq < 4; ++qq) {
            float4 a  = *(const float4*)(xb + j0 + qq * 8);
            float4 b2 = *(const float4*)(xb + j0 + qq * 8 + 4);
            v[qq] = pack8(a, b2);
          }
        } else {
          #pragma unroll
          for (int qq = 0; qq < 4; ++qq)
            #pragma unroll
            for (int e = 0; e < 8; ++e) {
              int j = j0 + qq * 8 + e;
              j = j < 0 ? -j : (j >= LSIG ? 2 * LSIG - 2 - j : j);
              v[qq][e] = bf16r(xb[j]);
            }
        }
      } else {
        #pragma unroll
        for (int qq = 0; qq < 4; ++qq) v[qq] = (short8)(short)0;
      }
      #pragma unroll
      for (int qq = 0; qq < 4; ++qq) *(short8*)&sB[sr][sh + qq * 8] = v[qq];
    }
    __syncthreads();

    const int ra = lane & 15;
    #pragma unroll
    for (int kk = 0; kk < 64; kk += 32) {
      const int col = kk + (lane >> 4) * 8;
      short8 arr[4], aii[4], bfr[4];
      #pragma unroll
      for (int i = 0; i < 4; ++i) {
        const int rm = (wave >> 1) * 64 + i * 16 + ra;
        arr[i] = *(const short8*)&sA[0][rm][col];
        aii[i] = *(const short8*)&sA[1][rm][col];
        const int rn = (wave & 1) * 64 + i * 16 + ra;
        bfr[i] = *(const short8*)&sB[rn][col];
      }
      #pragma unroll
      for (int i = 0; i < 4; ++i)
        #pragma unroll
        for (int j = 0; j < 4; ++j) {
          acc_r[i][j] = __builtin_amdgcn_mfma_f32_16x16x32_bf16(arr[i], bfr[j], acc_r[i][j], 0, 0, 0);
          acc_i[i][j] = __builtin_amdgcn_mfma_f32_16x16x32_bf16(aii[i], bfr[j], acc_i[i][j], 0, 0, 0);
        }
    }
    __syncthreads();
  }

  const int wm0 = m0 + (wave >> 1) * 64;
  const int wn0 = n0 + (wave & 1) * 64;
  const int cl = lane & 15;
  const int rg = (lane >> 4) * 4;
  #pragma unroll
  for (int j = 0; j < 4; ++j) {
    const int f = wn0 + j * 16 + cl;
    if (f >= NFR) continue;
    const int b = f / TFR, t = f - b * TFR;
    float* ob = out + (size_t)b * (CUT * TFR) + t;
    #pragma unroll
    for (int i = 0; i < 4; ++i) {
      #pragma unroll
      for (int r = 0; r < 4; ++r) {
        const int k = wm0 + i * 16 + rg + r;
        if (k < CUT) {
          float re = acc_r[i][j][r], im = acc_i[i][j][r];
          ob[(size_t)k * TFR] = sqrtf(re * re + im * im);
        }
      }
    }
  }
}

extern "C" void kernel_launch(void* const* d_in, const int* in_sizes, int n_in,
                              void* d_out, int out_size, void* d_ws, size_t ws_size,
                              hipStream_t stream) {
  const float* x     = (const float*)d_in[0];
  const float* basis = (const float*)d_in[1];
  float* out = (float*)d_out;

  const size_t hbytes = 2048 * sizeof(float);                    // 8 KB
  const size_t tbytes = 1024 * sizeof(float2);                   // 8 KB each
  const size_t mbytes = (size_t)NFR * MWS * sizeof(ushort);      // 43,589,632

  if (ws_size >= hbytes + 2 * tbytes + mbytes) {
    float*  hann = (float*)d_ws;
    float2* Tst  = (float2*)((char*)d_ws + hbytes);
    float2* Tun  = (float2*)((char*)d_ws + hbytes + tbytes);
    ushort* MW   = (ushort*)((char*)d_ws + hbytes + 2 * tbytes);
    make_tables<<<8, 256, 0, stream>>>(hann, Tst, Tun);
    stft_fft<<<NFR / 4, 256, 0, stream>>>(x, hann, Tst, Tun, MW);
    transpose_out<<<dim3(KT * TT, NBATCH), 256, 0, stream>>>(MW, out);
  } else {
    stft_gemm_fb<<<dim3(157, 9), 256, 0, stream>>>(basis, x, out);
  }
}

// Round 19
// 89.213 us; speedup vs baseline: 1.0673x; 1.0673x over previous
//
#include <hip/hip_runtime.h>
#include <hip/hip_bf16.h>
#include <cstdint>

// STFT magnitude via real-packed radix-4 FFT (round 19 = exact r17 revert).
// r18 (tst -> global) regressed: occupancy did NOT rise at the 4->5 block LDS
// step (38.7 -> 38.9%) while VALUBusy fell 55 -> 48% -- global twiddle reads
// sit on the butterfly dependent chain (~180cyc each, consumed immediately),
// and there were no extra waves to hide them. Lesson (r11 + r18): twiddles on
// the critical path must come from LDS or registers, never global.
// r17 structure: no pad kernel (direct f32 x reads, wave-uniform reflect
// branch), stages 0+2 and 4+6 in registers (r14-verified math incl. stage-4
// STRIDE=16 fix), stage 8 via LDS tst, mirror-pair unpack, coalesced bf16
// MW[f][k], r9-proven transpose. fft: VGPR 60, LDS 40960, 4 blocks/CU.

#define FILT   2048
#define HOP    512
#define CUT    1025
#define NBATCH 32
#define TFR    626
#define NFR    (NBATCH * TFR)      // 20032
#define LSIG   320000
#define N2     1024                // complex FFT length
#define MWS    1088                // mag_ws row stride (bf16), 128B-aligned
#define KT     17                  // k-tiles (ceil 1025/64)
#define TT     20                  // t-tiles (ceil 626/32)

typedef __attribute__((ext_vector_type(8))) short short8;

__device__ __forceinline__ short bf16r(float f) {
  __hip_bfloat16 h = __float2bfloat16(f);
  return __builtin_bit_cast(short, h);
}
__device__ __forceinline__ float bf2f(uint32_t u) {
  return __builtin_bit_cast(float, u << 16);
}

__device__ __forceinline__ short8 pack8(float4 a, float4 b) {
  short8 v;
  v[0] = bf16r(a.x); v[1] = bf16r(a.y); v[2] = bf16r(a.z); v[3] = bf16r(a.w);
  v[4] = bf16r(b.x); v[5] = bf16r(b.y); v[6] = bf16r(b.z); v[7] = bf16r(b.w);
  return v;
}

// -------- stage 1: twiddle + hann tables --------
__global__ void make_tables(float* __restrict__ hann, float2* __restrict__ Tst,
                            float2* __restrict__ Tun) {
  const int i = blockIdx.x * 256 + threadIdx.x;    // 0..2047
  const float PI2 = 6.283185307179586f;
  if (i < 2048) hann[i] = 0.5f - 0.5f * cosf(PI2 * (float)i / 2048.0f);
  if (i < 1024) {
    float s, c;
    sincosf(-PI2 * (float)i / 1024.0f, &s, &c);
    Tst[i] = make_float2(c, s);                    // W_1024^i (forward)
    sincosf(-PI2 * (float)i / 2048.0f, &s, &c);
    Tun[i] = make_float2(c, s);                    // W_2048^i (unpack)
  }
}

__device__ __forceinline__ float2 cmul(float2 a, float2 b) {
  return make_float2(a.x * b.x - a.y * b.y, a.x * b.y + a.y * b.x);
}
__device__ __forceinline__ float2 cmulc(float2 a, float cx, float cy) {
  return make_float2(a.x * cx - a.y * cy, a.x * cy + a.y * cx);
}

__device__ __forceinline__ int SW(int i) { return i ^ ((i >> 4) & 15); }

// natural-order 16-pt DFT in registers (r10/r14/r15-verified); literal twiddles
__device__ __forceinline__ void fft16(float2* y) {
  static constexpr float TX[4][4] = {
    {1.f, 1.f, 1.f, 1.f},
    {1.f,  0.92387953251128674f,  0.70710678118654752f,  0.38268343236508978f},
    {1.f,  0.70710678118654752f,  0.f,                  -0.70710678118654752f},
    {1.f,  0.38268343236508978f, -0.70710678118654752f, -0.92387953251128674f}};
  static constexpr float TY[4][4] = {
    {0.f, 0.f, 0.f, 0.f},
    {0.f, -0.38268343236508978f, -0.70710678118654752f, -0.92387953251128674f},
    {0.f, -0.70710678118654752f, -1.f,                  -0.70710678118654752f},
    {0.f, -0.92387953251128674f, -0.70710678118654752f,  0.38268343236508978f}};
  float2 G[16];
  #pragma unroll
  for (int n0 = 0; n0 < 4; ++n0) {
    float2 a0 = y[n0], a1 = y[n0 + 4], a2 = y[n0 + 8], a3 = y[n0 + 12];
    float2 e = make_float2(a0.x + a2.x, a0.y + a2.y);
    float2 f = make_float2(a0.x - a2.x, a0.y - a2.y);
    float2 g = make_float2(a1.x + a3.x, a1.y + a3.y);
    float2 h = make_float2(a1.x - a3.x, a1.y - a3.y);
    float2 F0 = make_float2(e.x + g.x, e.y + g.y);
    float2 F1 = make_float2(f.x + h.y, f.y - h.x);   // f - i*h
    float2 F2 = make_float2(e.x - g.x, e.y - g.y);
    float2 F3 = make_float2(f.x - h.y, f.y + h.x);   // f + i*h
    G[n0 * 4 + 0] = F0;
    G[n0 * 4 + 1] = cmulc(F1, TX[n0][1], TY[n0][1]);
    G[n0 * 4 + 2] = cmulc(F2, TX[n0][2], TY[n0][2]);
    G[n0 * 4 + 3] = cmulc(F3, TX[n0][3], TY[n0][3]);
  }
  #pragma unroll
  for (int q = 0; q < 4; ++q) {
    float2 a0 = G[q], a1 = G[4 + q], a2 = G[8 + q], a3 = G[12 + q];
    float2 e = make_float2(a0.x + a2.x, a0.y + a2.y);
    float2 f = make_float2(a0.x - a2.x, a0.y - a2.y);
    float2 g = make_float2(a1.x + a3.x, a1.y + a3.y);
    float2 h = make_float2(a1.x - a3.x, a1.y - a3.y);
    y[q]      = make_float2(e.x + g.x, e.y + g.y);
    y[q + 4]  = make_float2(f.x + h.y, f.y - h.x);
    y[q + 8]  = make_float2(e.x - g.x, e.y - g.y);
    y[q + 12] = make_float2(f.x - h.y, f.y + h.x);
  }
}

// radix-4 DIT stage via LDS (r8-proven), used for LOG=8 only
template<int LOG>
__device__ __forceinline__ void fft_stage(float2* z, const float2* tw, int lane) {
  constexpr int M4 = 1 << LOG;
  constexpr int STRIDE = 1 << (8 - LOG);
  #pragma unroll
  for (int u = 0; u < 4; ++u) {
    const int bf = u * 64 + lane;
    const int j  = bf & (M4 - 1);
    const int i0 = ((bf >> LOG) << (LOG + 2)) | j;
    const int i1 = i0 + M4, i2 = i0 + 2 * M4, i3 = i0 + 3 * M4;
    const int p0 = SW(i0), p1 = SW(i1), p2 = SW(i2), p3 = SW(i3);
    float2 a = z[p0], b = z[p1], c = z[p2], d = z[p3];
    if (LOG > 0) {
      b = cmul(b, tw[j * STRIDE]);
      c = cmul(c, tw[2 * j * STRIDE]);
      d = cmul(d, tw[3 * j * STRIDE]);
    }
    const float2 t0 = make_float2(a.x + c.x, a.y + c.y);
    const float2 t1 = make_float2(a.x - c.x, a.y - c.y);
    const float2 t2 = make_float2(b.x + d.x, b.y + d.y);
    const float2 t3 = make_float2(b.x - d.x, b.y - d.y);
    z[p0] = make_float2(t0.x + t2.x, t0.y + t2.y);
    z[p1] = make_float2(t1.x + t3.y, t1.y - t3.x);   // t1 - i*t3
    z[p2] = make_float2(t0.x - t2.x, t0.y - t2.y);
    z[p3] = make_float2(t1.x - t3.y, t1.y + t3.x);   // t1 + i*t3
  }
}

// -------- stage 2: windowed rFFT magnitude -> bf16 MW[f][k] coalesced --------
__global__ __launch_bounds__(256)
void stft_fft(const float* __restrict__ x, const float* __restrict__ hann,
              const float2* __restrict__ Tst, const float2* __restrict__ Tun,
              ushort* __restrict__ MW)
{
  __shared__ float2 zsh[4][1024];    // per-wave z, XOR-swizzled   32768 B
  __shared__ float2 tst[1024];       // stage twiddles              8192 B  (40960 total)

  const int tid = threadIdx.x, wv = tid >> 6, lane = tid & 63;
  #pragma unroll
  for (int u = 0; u < 4; ++u) tst[u * 256 + tid] = Tst[u * 256 + tid];
  __syncthreads();                   // tables ready; the ONLY barrier

  float2* z = zsh[wv];

  // per-lane geometry
  const int G  = ((lane & 3) << 4) | (lane & 12) | (lane >> 4);  // base-4 reverse
  const int zb = 16 * G, gm = G & 15;
  const int j0 = lane & 15, B = lane >> 4;

  const int f = blockIdx.x * 4 + wv;              // 1 frame per wave, grid NFR/4
  const int b = f / TFR, t = f - b * TFR;
  const float* xb = x + (size_t)b * LSIG;
  const int off = t * HOP - 1024;

  // load f32 pairs directly, window, stages 0+2 in registers, scatter
  float2 y[16];
  if (t >= 2 && t <= 623) {                       // interior: off>=0, off+2047<LSIG
    #pragma unroll
    for (int u = 0; u < 16; ++u) {
      const int n = u * 64 + lane;
      const float2 p = *(const float2*)(xb + off + 2 * n);
      const float2 h = *(const float2*)(hann + 2 * n);
      y[u] = make_float2(p.x * h.x, p.y * h.y);
    }
  } else {                                        // boundary: per-element reflect
    #pragma unroll
    for (int u = 0; u < 16; ++u) {
      const int n = u * 64 + lane;
      int ja = off + 2 * n, jb = ja + 1;
      ja = ja < 0 ? -ja : (ja >= LSIG ? 2 * LSIG - 2 - ja : ja);
      jb = jb < 0 ? -jb : (jb >= LSIG ? 2 * LSIG - 2 - jb : jb);
      const float2 h = *(const float2*)(hann + 2 * n);
      y[u] = make_float2(xb[ja] * h.x, xb[jb] * h.y);
    }
  }
  fft16(y);
  #pragma unroll
  for (int k = 0; k < 16; ++k) z[zb + (k ^ gm)] = y[k];

  // stages 4+6 in registers on closed set {j0 + 16a + 64b2 + 256B} (r14 math)
  {
    float2 g[4][4];
    #pragma unroll
    for (int a = 0; a < 4; ++a)
      #pragma unroll
      for (int b2 = 0; b2 < 4; ++b2)
        g[a][b2] = z[16 * (a + 4 * b2 + 16 * B) + (j0 ^ (a + 4 * b2))];
    // stage 4 (over a): STRIDE=16 -> twiddles tst[16*j0 * {1,2,3}]
    const float2 w41 = tst[16 * j0], w42 = tst[32 * j0], w43 = tst[48 * j0];
    #pragma unroll
    for (int b2 = 0; b2 < 4; ++b2) {
      float2 a0 = g[0][b2];
      float2 a1 = cmul(g[1][b2], w41);
      float2 a2 = cmul(g[2][b2], w42);
      float2 a3 = cmul(g[3][b2], w43);
      const float2 t0 = make_float2(a0.x + a2.x, a0.y + a2.y);
      const float2 t1 = make_float2(a0.x - a2.x, a0.y - a2.y);
      const float2 t2 = make_float2(a1.x + a3.x, a1.y + a3.y);
      const float2 t3 = make_float2(a1.x - a3.x, a1.y - a3.y);
      g[0][b2] = make_float2(t0.x + t2.x, t0.y + t2.y);
      g[1][b2] = make_float2(t1.x + t3.y, t1.y - t3.x);
      g[2][b2] = make_float2(t0.x - t2.x, t0.y - t2.y);
      g[3][b2] = make_float2(t1.x - t3.y, t1.y + t3.x);
    }
    // stage 6 (over b2): STRIDE=4 -> twiddles tst[4*(j0+16*mp) * {1,2,3}]
    #pragma unroll
    for (int mp = 0; mp < 4; ++mp) {
      const int jj = 4 * (j0 + 16 * mp);
      float2 a0 = g[mp][0];
      float2 a1 = cmul(g[mp][1], tst[jj]);
      float2 a2 = cmul(g[mp][2], tst[2 * jj]);
      float2 a3 = cmul(g[mp][3], tst[3 * jj]);
      const float2 t0 = make_float2(a0.x + a2.x, a0.y + a2.y);
      const float2 t1 = make_float2(a0.x - a2.x, a0.y - a2.y);
      const float2 t2 = make_float2(a1.x + a3.x, a1.y + a3.y);
      const float2 t3 = make_float2(a1.x - a3.x, a1.y - a3.y);
      g[mp][0] = make_float2(t0.x + t2.x, t0.y + t2.y);
      g[mp][1] = make_float2(t1.x + t3.y, t1.y - t3.x);
      g[mp][2] = make_float2(t0.x - t2.x, t0.y - t2.y);
      g[mp][3] = make_float2(t1.x - t3.y, t1.y + t3.x);
    }
    #pragma unroll
    for (int mp = 0; mp < 4; ++mp)
      #pragma unroll
      for (int m2 = 0; m2 < 4; ++m2)
        z[16 * (mp + 4 * m2 + 16 * B) + (j0 ^ (mp + 4 * m2))] = g[mp][m2];
  }

  fft_stage<8>(z, tst, lane);

  // mirror-pair unpack -> bf16 MW[f][*] (both directions coalesced)
  ushort* mw = MW + (size_t)f * MWS;
  #pragma unroll
  for (int v = 0; v < 8; ++v) {
    const int k = v * 64 + lane;                     // 0..511
    const float2 Zk = z[SW(k)];
    const int km = (N2 - k) & (N2 - 1);
    const float2 Zm = z[SW(km)];
    const float xer = 0.5f * (Zk.x + Zm.x);
    const float xei = 0.5f * (Zk.y - Zm.y);
    const float xor_ = 0.5f * (Zk.y + Zm.y);
    const float xoi = -0.5f * (Zk.x - Zm.x);
    const float2 w = Tun[k];                         // global, coalesced, L1-hot
    const float px = w.x * xor_ - w.y * xoi;
    const float py = w.x * xoi + w.y * xor_;
    const float Xr = xer + px, Xi = xei + py;
    const float Yr = xer - px, Yi = xei - py;
    mw[k]        = (ushort)bf16r(sqrtf(Xr * Xr + Xi * Xi));
    mw[1024 - k] = (ushort)bf16r(sqrtf(Yr * Yr + Yi * Yi));
  }
  if (lane == 0) {                                   // k=512 self-paired
    const float2 Zc = z[SW(512)];
    mw[512] = (ushort)bf16r(sqrtf(Zc.x * Zc.x + Zc.y * Zc.y));
  }
}

// -------- stage 3: transpose [f][k] bf16 -> out[b][k][t] f32 (r9-proven) --------
__global__ __launch_bounds__(256)
void transpose_out(const ushort* __restrict__ MW, float* __restrict__ out) {
  __shared__ float tile[64][33];
  const int b  = blockIdx.y;
  const int kt = blockIdx.x % KT;
  const int tt = blockIdx.x / KT;
  const int k0 = kt * 64, t0 = tt * 32;
  const int tid = threadIdx.x;
  const int r = tid >> 5, c = tid & 31;

  #pragma unroll
  for (int s = 0; s < 4; ++s) {
    const int t = t0 + r + 8 * s;
    if (t < TFR) {
      const uint32_t pr =
        *(const uint32_t*)(MW + (size_t)(b * TFR + t) * MWS + k0 + 2 * c);
      tile[2 * c][r + 8 * s]     = bf2f(pr & 0xffffu);
      tile[2 * c + 1][r + 8 * s] = bf2f(pr >> 16);
    }
  }
  __syncthreads();

  const int kk = tid >> 2, toff = (tid & 3) * 8;
  const int k = k0 + kk;
  if (k < CUT) {
    float* pptr = out + (size_t)b * (CUT * TFR) + (size_t)k * TFR + t0 + toff;
    if (t0 + 32 <= TFR) {
      float4 v0 = make_float4(tile[kk][toff], tile[kk][toff + 1],
                              tile[kk][toff + 2], tile[kk][toff + 3]);
      float4 v1 = make_float4(tile[kk][toff + 4], tile[kk][toff + 5],
                              tile[kk][toff + 6], tile[kk][toff + 7]);
      *(float4*)pptr = v0;
      *(float4*)(pptr + 4) = v1;
    } else {
      #pragma unroll
      for (int e = 0; e < 8; ++e) {
        const int t = t0 + toff + e;
        if (t < TFR) pptr[e] = tile[kk][toff + e];
      }
    }
  }
}

// -------- fallback: reg-staged 128x128 MFMA GEMM (no ws needed) --------
typedef __attribute__((ext_vector_type(4))) float f32x4;

__global__ __launch_bounds__(256, 2)
void stft_gemm_fb(const float* __restrict__ basis, const float* __restrict__ x,
                  float* __restrict__ out)
{
  __shared__ alignas(16) short sA[2][128][64];
  __shared__ alignas(16) short sB[128][64];

  const int tid  = threadIdx.x;
  const int wave = tid >> 6;
  const int lane = tid & 63;
  const int n0 = blockIdx.x * 128;
  const int m0 = blockIdx.y * 128;

  f32x4 acc_r[4][4], acc_i[4][4];
  #pragma unroll
  for (int i = 0; i < 4; ++i)
    #pragma unroll
    for (int j = 0; j < 4; ++j) { acc_r[i][j] = (f32x4)0.f; acc_i[i][j] = (f32x4)0.f; }

  const int sr = tid >> 1;
  const int sh = (tid & 1) * 32;

  for (int k0 = 0; k0 < FILT; k0 += 64) {
    #pragma unroll
    for (int p = 0; p < 2; ++p) {
      const int k = m0 + sr;
      short8 v[4];
      if (k < CUT) {
        const float* src = basis + (size_t)(p * CUT + k) * FILT + k0 + sh;
        #pragma unroll
        for (int qq = 0; qq < 4; ++qq) {
          float4 a = *(const float4*)(src + qq * 8);
          float4 b = *(const float4*)(src + qq * 8 + 4);
          v[qq] = pack8(a, b);
        }
      } else {
        #pragma unroll
        for (int qq = 0; qq < 4; ++qq) v[qq] = (short8)(short)0;
      }
      #pragma unroll
      for (int qq = 0; qq < 4; ++qq) *(short8*)&sA[p][sr][sh + qq * 8] = v[qq];
    }
    {
      const int f = n0 + sr;
      short8 v[4];
      if (f < NFR) {
        const int b = f / TFR, t = f - b * TFR;
        const float* xb = x + (size_t)b * LSIG;
        const int j0 = t * HOP + k0 + sh - 1024;
        if (j0 >= 0 && j0 + 32 <= LSIG) {
          #pragma unroll
          for (int qq = 0; qq < 4; ++qq) {
            float4 a  = *(const float4*)(xb + j0 + qq * 8);
            float4 b2 = *(const float4*)(xb + j0 + qq * 8 + 4);
            v[qq] = pack8(a, b2);
          }
        } else {
          #pragma unroll
          for (int qq = 0; qq < 4; ++qq)
            #pragma unroll
            for (int e = 0; e < 8; ++e) {
              int j = j0 + qq * 8 + e;
              j = j < 0 ? -j : (j >= LSIG ? 2 * LSIG - 2 - j : j);
              v[qq][e] = bf16r(xb[j]);
            }
        }
      } else {
        #pragma unroll
        for (int qq = 0; qq < 4; ++qq) v[qq] = (short8)(short)0;
      }
      #pragma unroll
      for (int qq = 0; qq < 4; ++qq) *(short8*)&sB[sr][sh + qq * 8] = v[qq];
    }
    __syncthreads();

    const int ra = lane & 15;
    #pragma unroll
    for (int kk = 0; kk < 64; kk += 32) {
      const int col = kk + (lane >> 4) * 8;
      short8 arr[4], aii[4], bfr[4];
      #pragma unroll
      for (int i = 0; i < 4; ++i) {
        const int rm = (wave >> 1) * 64 + i * 16 + ra;
        arr[i] = *(const short8*)&sA[0][rm][col];
        aii[i] = *(const short8*)&sA[1][rm][col];
        const int rn = (wave & 1) * 64 + i * 16 + ra;
        bfr[i] = *(const short8*)&sB[rn][col];
      }
      #pragma unroll
      for (int i = 0; i < 4; ++i)
        #pragma unroll
        for (int j = 0; j < 4; ++j) {
          acc_r[i][j] = __builtin_amdgcn_mfma_f32_16x16x32_bf16(arr[i], bfr[j], acc_r[i][j], 0, 0, 0);
          acc_i[i][j] = __builtin_amdgcn_mfma_f32_16x16x32_bf16(aii[i], bfr[j], acc_i[i][j], 0, 0, 0);
        }
    }
    __syncthreads();
  }

  const int wm0 = m0 + (wave >> 1) * 64;
  const int wn0 = n0 + (wave & 1) * 64;
  const int cl = lane & 15;
  const int rg = (lane >> 4) * 4;
  #pragma unroll
  for (int j = 0; j < 4; ++j) {
    const int f = wn0 + j * 16 + cl;
    if (f >= NFR) continue;
    const int b = f / TFR, t = f - b * TFR;
    float* ob = out + (size_t)b * (CUT * TFR) + t;
    #pragma unroll
    for (int i = 0; i < 4; ++i) {
      #pragma unroll
      for (int r = 0; r < 4; ++r) {
        const int k = wm0 + i * 16 + rg + r;
        if (k < CUT) {
          float re = acc_r[i][j][r], im = acc_i[i][j][r];
          ob[(size_t)k * TFR] = sqrtf(re * re + im * im);
        }
      }
    }
  }
}

extern "C" void kernel_launch(void* const* d_in, const int* in_sizes, int n_in,
                              void* d_out, int out_size, void* d_ws, size_t ws_size,
                              hipStream_t stream) {
  const float* x     = (const float*)d_in[0];
  const float* basis = (const float*)d_in[1];
  float* out = (float*)d_out;

  const size_t hbytes = 2048 * sizeof(float);                    // 8 KB
  const size_t tbytes = 1024 * sizeof(float2);                   // 8 KB each
  const size_t mbytes = (size_t)NFR * MWS * sizeof(ushort);      // 43,589,632

  if (ws_size >= hbytes + 2 * tbytes + mbytes) {
    float*  hann = (float*)d_ws;
    float2* Tst  = (float2*)((char*)d_ws + hbytes);
    float2* Tun  = (float2*)((char*)d_ws + hbytes + tbytes);
    ushort* MW   = (ushort*)((char*)d_ws + hbytes + 2 * tbytes);
    make_tables<<<8, 256, 0, stream>>>(hann, Tst, Tun);
    stft_fft<<<NFR / 4, 256, 0, stream>>>(x, hann, Tst, Tun, MW);
    transpose_out<<<dim3(KT * TT, NBATCH), 256, 0, stream>>>(MW, out);
  } else {
    stft_gemm_fb<<<dim3(157, 9), 256, 0, stream>>>(basis, x, out);
  }
}

// Round 20
// 86.321 us; speedup vs baseline: 1.1031x; 1.0335x over previous
//
#include <hip/hip_runtime.h>
#include <hip/hip_bf16.h>
#include <cstdint>

// STFT magnitude via real-packed radix-4 FFT (round 20 = r17 + packed-f32 math).
// Identical structure to r17/r19 (champion, 89us): no pad kernel, stages 0+2
// and 4+6 in registers, stage 8 via LDS tst, mirror-pair unpack, coalesced
// bf16 MW[f][k], r9-proven transpose. ONE change: all complex butterfly
// arithmetic is rewritten on ext_vector_type(2) float so LLVM emits packed
// VOP3P f32 ops (v_pk_add_f32 / v_pk_fma_f32, op_sel swizzles, neg mods):
//   complex add/sub: 1 pk op (was 2 scalar); cmul/cmulc: 2 pk ops (was 4).
// Mechanism: fft kernel showed 41us of VALU ISSUE (55% x 74us) vs ~13us f32
// FLOP floor -- instruction count, not FLOPs, is the cost. Indexing/LDS layout
// byte-identical (f2 == float2 in memory). All +/-i sign sites re-derived.

#define FILT   2048
#define HOP    512
#define CUT    1025
#define NBATCH 32
#define TFR    626
#define NFR    (NBATCH * TFR)      // 20032
#define LSIG   320000
#define N2     1024                // complex FFT length
#define MWS    1088                // mag_ws row stride (bf16), 128B-aligned
#define KT     17                  // k-tiles (ceil 1025/64)
#define TT     20                  // t-tiles (ceil 626/32)

typedef __attribute__((ext_vector_type(8))) short short8;
typedef __attribute__((ext_vector_type(2))) float f2;

__device__ __forceinline__ f2 mkf2(float a, float b) { f2 r; r.x = a; r.y = b; return r; }

__device__ __forceinline__ short bf16r(float f) {
  __hip_bfloat16 h = __float2bfloat16(f);
  return __builtin_bit_cast(short, h);
}
__device__ __forceinline__ float bf2f(uint32_t u) {
  return __builtin_bit_cast(float, u << 16);
}

__device__ __forceinline__ short8 pack8(float4 a, float4 b) {
  short8 v;
  v[0] = bf16r(a.x); v[1] = bf16r(a.y); v[2] = bf16r(a.z); v[3] = bf16r(a.w);
  v[4] = bf16r(b.x); v[5] = bf16r(b.y); v[6] = bf16r(b.z); v[7] = bf16r(b.w);
  return v;
}

// -------- stage 1: twiddle + hann tables --------
__global__ void make_tables(float* __restrict__ hann, float2* __restrict__ Tst,
                            float2* __restrict__ Tun) {
  const int i = blockIdx.x * 256 + threadIdx.x;    // 0..2047
  const float PI2 = 6.283185307179586f;
  if (i < 2048) hann[i] = 0.5f - 0.5f * cosf(PI2 * (float)i / 2048.0f);
  if (i < 1024) {
    float s, c;
    sincosf(-PI2 * (float)i / 1024.0f, &s, &c);
    Tst[i] = make_float2(c, s);                    // W_1024^i (forward)
    sincosf(-PI2 * (float)i / 2048.0f, &s, &c);
    Tun[i] = make_float2(c, s);                    // W_2048^i (unpack)
  }
}

// packed complex mul: (ax bx - ay by, ax by + ay bx) = a.xx*b + {-ay,ay}*b.yx
__device__ __forceinline__ f2 cmul(f2 a, f2 b) {
  return a.xx * b + mkf2(-a.y, a.y) * b.yx;
}
__device__ __forceinline__ f2 cmulc(f2 a, float cx, float cy) {
  return a.xx * mkf2(cx, cy) + mkf2(-a.y, a.y) * mkf2(cy, cx);
}

__device__ __forceinline__ int SW(int i) { return i ^ ((i >> 4) & 15); }

// natural-order 16-pt DFT in registers (r10/r14/r15-verified math, packed ops)
__device__ __forceinline__ void fft16(f2* y) {
  static constexpr float TX[4][4] = {
    {1.f, 1.f, 1.f, 1.f},
    {1.f,  0.92387953251128674f,  0.70710678118654752f,  0.38268343236508978f},
    {1.f,  0.70710678118654752f,  0.f,                  -0.70710678118654752f},
    {1.f,  0.38268343236508978f, -0.70710678118654752f, -0.92387953251128674f}};
  static constexpr float TY[4][4] = {
    {0.f, 0.f, 0.f, 0.f},
    {0.f, -0.38268343236508978f, -0.70710678118654752f, -0.92387953251128674f},
    {0.f, -0.70710678118654752f, -1.f,                  -0.70710678118654752f},
    {0.f, -0.92387953251128674f, -0.70710678118654752f,  0.38268343236508978f}};
  f2 G[16];
  #pragma unroll
  for (int n0 = 0; n0 < 4; ++n0) {
    f2 a0 = y[n0], a1 = y[n0 + 4], a2 = y[n0 + 8], a3 = y[n0 + 12];
    f2 e = a0 + a2, f = a0 - a2, g = a1 + a3, h = a1 - a3;
    f2 hs = mkf2(h.y, -h.x);                     // -i*h adds as f + hs
    G[n0 * 4 + 0] = e + g;
    G[n0 * 4 + 1] = cmulc(f + hs, TX[n0][1], TY[n0][1]);
    G[n0 * 4 + 2] = cmulc(e - g, TX[n0][2], TY[n0][2]);
    G[n0 * 4 + 3] = cmulc(f - hs, TX[n0][3], TY[n0][3]);
  }
  #pragma unroll
  for (int q = 0; q < 4; ++q) {
    f2 a0 = G[q], a1 = G[4 + q], a2 = G[8 + q], a3 = G[12 + q];
    f2 e = a0 + a2, f = a0 - a2, g = a1 + a3, h = a1 - a3;
    f2 hs = mkf2(h.y, -h.x);
    y[q]      = e + g;
    y[q + 4]  = f + hs;
    y[q + 8]  = e - g;
    y[q + 12] = f - hs;
  }
}

// radix-4 DIT stage via LDS (r8-proven indexing), packed ops; LOG=8 only
template<int LOG>
__device__ __forceinline__ void fft_stage(f2* z, const f2* tw, int lane) {
  constexpr int M4 = 1 << LOG;
  constexpr int STRIDE = 1 << (8 - LOG);
  #pragma unroll
  for (int u = 0; u < 4; ++u) {
    const int bf = u * 64 + lane;
    const int j  = bf & (M4 - 1);
    const int i0 = ((bf >> LOG) << (LOG + 2)) | j;
    const int i1 = i0 + M4, i2 = i0 + 2 * M4, i3 = i0 + 3 * M4;
    const int p0 = SW(i0), p1 = SW(i1), p2 = SW(i2), p3 = SW(i3);
    f2 a = z[p0], b = z[p1], c = z[p2], d = z[p3];
    if (LOG > 0) {
      b = cmul(b, tw[j * STRIDE]);
      c = cmul(c, tw[2 * j * STRIDE]);
      d = cmul(d, tw[3 * j * STRIDE]);
    }
    f2 t0 = a + c, t1 = a - c, t2 = b + d, t3 = b - d;
    f2 hs = mkf2(t3.y, -t3.x);
    z[p0] = t0 + t2;
    z[p1] = t1 + hs;                             // t1 - i*t3
    z[p2] = t0 - t2;
    z[p3] = t1 - hs;                             // t1 + i*t3
  }
}

// -------- stage 2: windowed rFFT magnitude -> bf16 MW[f][k] coalesced --------
__global__ __launch_bounds__(256)
void stft_fft(const float* __restrict__ x, const float* __restrict__ hann,
              const f2* __restrict__ Tst, const f2* __restrict__ Tun,
              ushort* __restrict__ MW)
{
  __shared__ f2 zsh[4][1024];        // per-wave z, XOR-swizzled   32768 B
  __shared__ f2 tst[1024];           // stage twiddles              8192 B  (40960 total)

  const int tid = threadIdx.x, wv = tid >> 6, lane = tid & 63;
  #pragma unroll
  for (int u = 0; u < 4; ++u) tst[u * 256 + tid] = Tst[u * 256 + tid];
  __syncthreads();                   // tables ready; the ONLY barrier

  f2* z = zsh[wv];

  // per-lane geometry
  const int G  = ((lane & 3) << 4) | (lane & 12) | (lane >> 4);  // base-4 reverse
  const int zb = 16 * G, gm = G & 15;
  const int j0 = lane & 15, B = lane >> 4;

  const int f = blockIdx.x * 4 + wv;              // 1 frame per wave, grid NFR/4
  const int b = f / TFR, t = f - b * TFR;
  const float* xb = x + (size_t)b * LSIG;
  const int off = t * HOP - 1024;

  // load f32 pairs directly, window (packed mul), stages 0+2 in regs, scatter
  f2 y[16];
  if (t >= 2 && t <= 623) {                       // interior: off>=0, off+2047<LSIG
    #pragma unroll
    for (int u = 0; u < 16; ++u) {
      const int n = u * 64 + lane;
      const f2 p = *(const f2*)(xb + off + 2 * n);
      const f2 h = *(const f2*)(hann + 2 * n);
      y[u] = p * h;
    }
  } else {                                        // boundary: per-element reflect
    #pragma unroll
    for (int u = 0; u < 16; ++u) {
      const int n = u * 64 + lane;
      int ja = off + 2 * n, jb = ja + 1;
      ja = ja < 0 ? -ja : (ja >= LSIG ? 2 * LSIG - 2 - ja : ja);
      jb = jb < 0 ? -jb : (jb >= LSIG ? 2 * LSIG - 2 - jb : jb);
      const f2 h = *(const f2*)(hann + 2 * n);
      y[u] = mkf2(xb[ja], xb[jb]) * h;
    }
  }
  fft16(y);
  #pragma unroll
  for (int k = 0; k < 16; ++k) z[zb + (k ^ gm)] = y[k];

  // stages 4+6 in registers on closed set {j0 + 16a + 64b2 + 256B} (r14 math)
  {
    f2 g[4][4];
    #pragma unroll
    for (int a = 0; a < 4; ++a)
      #pragma unroll
      for (int b2 = 0; b2 < 4; ++b2)
        g[a][b2] = z[16 * (a + 4 * b2 + 16 * B) + (j0 ^ (a + 4 * b2))];
    // stage 4 (over a): STRIDE=16 -> twiddles tst[16*j0 * {1,2,3}]
    const f2 w41 = tst[16 * j0], w42 = tst[32 * j0], w43 = tst[48 * j0];
    #pragma unroll
    for (int b2 = 0; b2 < 4; ++b2) {
      f2 a0 = g[0][b2];
      f2 a1 = cmul(g[1][b2], w41);
      f2 a2 = cmul(g[2][b2], w42);
      f2 a3 = cmul(g[3][b2], w43);
      f2 t0 = a0 + a2, t1 = a0 - a2, t2 = a1 + a3, t3 = a1 - a3;
      f2 hs = mkf2(t3.y, -t3.x);
      g[0][b2] = t0 + t2;
      g[1][b2] = t1 + hs;
      g[2][b2] = t0 - t2;
      g[3][b2] = t1 - hs;
    }
    // stage 6 (over b2): STRIDE=4 -> twiddles tst[4*(j0+16*mp) * {1,2,3}]
    #pragma unroll
    for (int mp = 0; mp < 4; ++mp) {
      const int jj = 4 * (j0 + 16 * mp);
      f2 a0 = g[mp][0];
      f2 a1 = cmul(g[mp][1], tst[jj]);
      f2 a2 = cmul(g[mp][2], tst[2 * jj]);
      f2 a3 = cmul(g[mp][3], tst[3 * jj]);
      f2 t0 = a0 + a2, t1 = a0 - a2, t2 = a1 + a3, t3 = a1 - a3;
      f2 hs = mkf2(t3.y, -t3.x);
      g[mp][0] = t0 + t2;
      g[mp][1] = t1 + hs;
      g[mp][2] = t0 - t2;
      g[mp][3] = t1 - hs;
    }
    #pragma unroll
    for (int mp = 0; mp < 4; ++mp)
      #pragma unroll
      for (int m2 = 0; m2 < 4; ++m2)
        z[16 * (mp + 4 * m2 + 16 * B) + (j0 ^ (mp + 4 * m2))] = g[mp][m2];
  }

  fft_stage<8>(z, tst, lane);

  // mirror-pair unpack -> bf16 MW[f][*] (both directions coalesced)
  ushort* mw = MW + (size_t)f * MWS;
  #pragma unroll
  for (int v = 0; v < 8; ++v) {
    const int k = v * 64 + lane;                     // 0..511
    const f2 Zk = z[SW(k)];
    const int km = (N2 - k) & (N2 - 1);
    const f2 Zm = z[SW(km)];
    const f2 Xe = (Zk + mkf2(Zm.x, -Zm.y)) * 0.5f;   // (xer, xei)
    const f2 Xo = mkf2(Zk.y + Zm.y, Zm.x - Zk.x) * 0.5f;  // (xor, xoi)
    const f2 w = Tun[k];                             // global, coalesced, L1-hot
    const f2 wXo = cmul(w, Xo);                      // (px, py)
    const f2 X = Xe + wXo;
    const f2 Y = Xe - wXo;
    mw[k]        = (ushort)bf16r(sqrtf(X.x * X.x + X.y * X.y));
    mw[1024 - k] = (ushort)bf16r(sqrtf(Y.x * Y.x + Y.y * Y.y));
  }
  if (lane == 0) {                                   // k=512 self-paired
    const f2 Zc = z[SW(512)];
    mw[512] = (ushort)bf16r(sqrtf(Zc.x * Zc.x + Zc.y * Zc.y));
  }
}

// -------- stage 3: transpose [f][k] bf16 -> out[b][k][t] f32 (r9-proven) --------
__global__ __launch_bounds__(256)
void transpose_out(const ushort* __restrict__ MW, float* __restrict__ out) {
  __shared__ float tile[64][33];
  const int b  = blockIdx.y;
  const int kt = blockIdx.x % KT;
  const int tt = blockIdx.x / KT;
  const int k0 = kt * 64, t0 = tt * 32;
  const int tid = threadIdx.x;
  const int r = tid >> 5, c = tid & 31;

  #pragma unroll
  for (int s = 0; s < 4; ++s) {
    const int t = t0 + r + 8 * s;
    if (t < TFR) {
      const uint32_t pr =
        *(const uint32_t*)(MW + (size_t)(b * TFR + t) * MWS + k0 + 2 * c);
      tile[2 * c][r + 8 * s]     = bf2f(pr & 0xffffu);
      tile[2 * c + 1][r + 8 * s] = bf2f(pr >> 16);
    }
  }
  __syncthreads();

  const int kk = tid >> 2, toff = (tid & 3) * 8;
  const int k = k0 + kk;
  if (k < CUT) {
    float* pptr = out + (size_t)b * (CUT * TFR) + (size_t)k * TFR + t0 + toff;
    if (t0 + 32 <= TFR) {
      float4 v0 = make_float4(tile[kk][toff], tile[kk][toff + 1],
                              tile[kk][toff + 2], tile[kk][toff + 3]);
      float4 v1 = make_float4(tile[kk][toff + 4], tile[kk][toff + 5],
                              tile[kk][toff + 6], tile[kk][toff + 7]);
      *(float4*)pptr = v0;
      *(float4*)(pptr + 4) = v1;
    } else {
      #pragma unroll
      for (int e = 0; e < 8; ++e) {
        const int t = t0 + toff + e;
        if (t < TFR) pptr[e] = tile[kk][toff + e];
      }
    }
  }
}

// -------- fallback: reg-staged 128x128 MFMA GEMM (no ws needed) --------
typedef __attribute__((ext_vector_type(4))) float f32x4;

__global__ __launch_bounds__(256, 2)
void stft_gemm_fb(const float* __restrict__ basis, const float* __restrict__ x,
                  float* __restrict__ out)
{
  __shared__ alignas(16) short sA[2][128][64];
  __shared__ alignas(16) short sB[128][64];

  const int tid  = threadIdx.x;
  const int wave = tid >> 6;
  const int lane = tid & 63;
  const int n0 = blockIdx.x * 128;
  const int m0 = blockIdx.y * 128;

  f32x4 acc_r[4][4], acc_i[4][4];
  #pragma unroll
  for (int i = 0; i < 4; ++i)
    #pragma unroll
    for (int j = 0; j < 4; ++j) { acc_r[i][j] = (f32x4)0.f; acc_i[i][j] = (f32x4)0.f; }

  const int sr = tid >> 1;
  const int sh = (tid & 1) * 32;

  for (int k0 = 0; k0 < FILT; k0 += 64) {
    #pragma unroll
    for (int p = 0; p < 2; ++p) {
      const int k = m0 + sr;
      short8 v[4];
      if (k < CUT) {
        const float* src = basis + (size_t)(p * CUT + k) * FILT + k0 + sh;
        #pragma unroll
        for (int qq = 0; qq < 4; ++qq) {
          float4 a = *(const float4*)(src + qq * 8);
          float4 b = *(const float4*)(src + qq * 8 + 4);
          v[qq] = pack8(a, b);
        }
      } else {
        #pragma unroll
        for (int qq = 0; qq < 4; ++qq) v[qq] = (short8)(short)0;
      }
      #pragma unroll
      for (int qq = 0; qq < 4; ++qq) *(short8*)&sA[p][sr][sh + qq * 8] = v[qq];
    }
    {
      const int f = n0 + sr;
      short8 v[4];
      if (f < NFR) {
        const int b = f / TFR, t = f - b * TFR;
        const float* xb = x + (size_t)b * LSIG;
        const int j0 = t * HOP + k0 + sh - 1024;
        if (j0 >= 0 && j0 + 32 <= LSIG) {
          #pragma unroll
          for (int qq = 0; qq < 4; ++qq) {
            float4 a  = *(const float4*)(xb + j0 + qq * 8);
            float4 b2 = *(const float4*)(xb + j0 + qq * 8 + 4);
            v[qq] = pack8(a, b2);
          }
        } else {
          #pragma unroll
          for (int qq = 0; qq < 4; ++qq)
            #pragma unroll
            for (int e = 0; e < 8; ++e) {
              int j = j0 + qq * 8 + e;
              j = j < 0 ? -j : (j >= LSIG ? 2 * LSIG - 2 - j : j);
              v[qq][e] = bf16r(xb[j]);
            }
        }
      } else {
        #pragma unroll
        for (int qq = 0; qq < 4; ++qq) v[qq] = (short8)(short)0;
      }
      #pragma unroll
      for (int qq = 0; qq < 4; ++qq) *(short8*)&sB[sr][sh + qq * 8] = v[qq];
    }
    __syncthreads();

    const int ra = lane & 15;
    #pragma unroll
    for (int kk = 0; kk < 64; kk += 32) {
      const int col = kk + (lane >> 4) * 8;
      short8 arr[4], aii[4], bfr[4];
      #pragma unroll
      for (int i = 0; i < 4; ++i) {
        const int rm = (wave >> 1) * 64 + i * 16 + ra;
        arr[i] = *(const short8*)&sA[0][rm][col];
        aii[i] = *(const short8*)&sA[1][rm][col];
        const int rn = (wave & 1) * 64 + i * 16 + ra;
        bfr[i] = *(const short8*)&sB[rn][col];
      }
      #pragma unroll
      for (int i = 0; i < 4; ++i)
        #pragma unroll
        for (int j = 0; j < 4; ++j) {
          acc_r[i][j] = __builtin_amdgcn_mfma_f32_16x16x32_bf16(arr[i], bfr[j], acc_r[i][j], 0, 0, 0);
          acc_i[i][j] = __builtin_amdgcn_mfma_f32_16x16x32_bf16(aii[i], bfr[j], acc_i[i][j], 0, 0, 0);
        }
    }
    __syncthreads();
  }

  const int wm0 = m0 + (wave >> 1) * 64;
  const int wn0 = n0 + (wave & 1) * 64;
  const int cl = lane & 15;
  const int rg = (lane >> 4) * 4;
  #pragma unroll
  for (int j = 0; j < 4; ++j) {
    const int f = wn0 + j * 16 + cl;
    if (f >= NFR) continue;
    const int b = f / TFR, t = f - b * TFR;
    float* ob = out + (size_t)b * (CUT * TFR) + t;
    #pragma unroll
    for (int i = 0; i < 4; ++i) {
      #pragma unroll
      for (int r = 0; r < 4; ++r) {
        const int k = wm0 + i * 16 + rg + r;
        if (k < CUT) {
          float re = acc_r[i][j][r], im = acc_i[i][j][r];
          ob[(size_t)k * TFR] = sqrtf(re * re + im * im);
        }
      }
    }
  }
}

extern "C" void kernel_launch(void* const* d_in, const int* in_sizes, int n_in,
                              void* d_out, int out_size, void* d_ws, size_t ws_size,
                              hipStream_t stream) {
  const float* x     = (const float*)d_in[0];
  const float* basis = (const float*)d_in[1];
  float* out = (float*)d_out;

  const size_t hbytes = 2048 * sizeof(float);                    // 8 KB
  const size_t tbytes = 1024 * sizeof(float2);                   // 8 KB each
  const size_t mbytes = (size_t)NFR * MWS * sizeof(ushort);      // 43,589,632

  if (ws_size >= hbytes + 2 * tbytes + mbytes) {
    float*  hann = (float*)d_ws;
    float2* Tst  = (float2*)((char*)d_ws + hbytes);
    float2* Tun  = (float2*)((char*)d_ws + hbytes + tbytes);
    ushort* MW   = (ushort*)((char*)d_ws + hbytes + 2 * tbytes);
    make_tables<<<8, 256, 0, stream>>>(hann, Tst, Tun);
    stft_fft<<<NFR / 4, 256, 0, stream>>>(x, hann, (const f2*)Tst, (const f2*)Tun, MW);
    transpose_out<<<dim3(KT * TT, NBATCH), 256, 0, stream>>>(MW, out);
  } else {
    stft_gemm_fb<<<dim3(157, 9), 256, 0, stream>>>(basis, x, out);
  }
}

// Round 21
// 86.143 us; speedup vs baseline: 1.1053x; 1.0021x over previous
//
#include <hip/hip_runtime.h>
#include <hip/hip_bf16.h>
#include <cstdint>

// STFT magnitude via real-packed radix-4 FFT (round 21 = r20 + fused stage8/unpack).
// r20 champion structure (packed f2 math, stages 0+2 and 4+6 in registers,
// one prologue barrier, coalesced bf16 MW[f][k], r9 transpose). NEW: stage 8
// and the rFFT unpack are FUSED in registers via mirror-line pairing:
//   line j outputs {X[j+256m]}; lines j and 256-j are mutually mirror-complete
//   (1024-(j+256m) = (256-j)+256(3-m)). Each lane butterflies BOTH lines
//   j1 = u*64+lane+1 and j2 = 256-j1 from gathered Z7 (8 reads + 6 tw), then
//   unpacks all 4 (Zk,Zm) pairs register-locally. j1=128 self-degenerates
//   correctly; line 0 ({0,256,512,768} + Nyquist 1024) is a lane-0 block.
// LDS ops for stage8+unpack: 60 -> 28 per lane; one serial round-trip removed.

#define FILT   2048
#define HOP    512
#define CUT    1025
#define NBATCH 32
#define TFR    626
#define NFR    (NBATCH * TFR)      // 20032
#define LSIG   320000
#define N2     1024                // complex FFT length
#define MWS    1088                // mag_ws row stride (bf16), 128B-aligned
#define KT     17                  // k-tiles (ceil 1025/64)
#define TT     20                  // t-tiles (ceil 626/32)

typedef __attribute__((ext_vector_type(8))) short short8;
typedef __attribute__((ext_vector_type(2))) float f2;

__device__ __forceinline__ f2 mkf2(float a, float b) { f2 r; r.x = a; r.y = b; return r; }

__device__ __forceinline__ short bf16r(float f) {
  __hip_bfloat16 h = __float2bfloat16(f);
  return __builtin_bit_cast(short, h);
}
__device__ __forceinline__ float bf2f(uint32_t u) {
  return __builtin_bit_cast(float, u << 16);
}

__device__ __forceinline__ short8 pack8(float4 a, float4 b) {
  short8 v;
  v[0] = bf16r(a.x); v[1] = bf16r(a.y); v[2] = bf16r(a.z); v[3] = bf16r(a.w);
  v[4] = bf16r(b.x); v[5] = bf16r(b.y); v[6] = bf16r(b.z); v[7] = bf16r(b.w);
  return v;
}

// -------- stage 1: twiddle + hann tables --------
__global__ void make_tables(float* __restrict__ hann, float2* __restrict__ Tst,
                            float2* __restrict__ Tun) {
  const int i = blockIdx.x * 256 + threadIdx.x;    // 0..2047
  const float PI2 = 6.283185307179586f;
  if (i < 2048) hann[i] = 0.5f - 0.5f * cosf(PI2 * (float)i / 2048.0f);
  if (i < 1024) {
    float s, c;
    sincosf(-PI2 * (float)i / 1024.0f, &s, &c);
    Tst[i] = make_float2(c, s);                    // W_1024^i (forward)
    sincosf(-PI2 * (float)i / 2048.0f, &s, &c);
    Tun[i] = make_float2(c, s);                    // W_2048^i (unpack)
  }
}

// packed complex mul: (ax bx - ay by, ax by + ay bx) = a.xx*b + {-ay,ay}*b.yx
__device__ __forceinline__ f2 cmul(f2 a, f2 b) {
  return a.xx * b + mkf2(-a.y, a.y) * b.yx;
}
__device__ __forceinline__ f2 cmulc(f2 a, float cx, float cy) {
  return a.xx * mkf2(cx, cy) + mkf2(-a.y, a.y) * mkf2(cy, cx);
}

__device__ __forceinline__ int SW(int i) { return i ^ ((i >> 4) & 15); }

// natural-order 16-pt DFT in registers (r10/r14/r15-verified math, packed ops)
__device__ __forceinline__ void fft16(f2* y) {
  static constexpr float TX[4][4] = {
    {1.f, 1.f, 1.f, 1.f},
    {1.f,  0.92387953251128674f,  0.70710678118654752f,  0.38268343236508978f},
    {1.f,  0.70710678118654752f,  0.f,                  -0.70710678118654752f},
    {1.f,  0.38268343236508978f, -0.70710678118654752f, -0.92387953251128674f}};
  static constexpr float TY[4][4] = {
    {0.f, 0.f, 0.f, 0.f},
    {0.f, -0.38268343236508978f, -0.70710678118654752f, -0.92387953251128674f},
    {0.f, -0.70710678118654752f, -1.f,                  -0.70710678118654752f},
    {0.f, -0.92387953251128674f, -0.70710678118654752f,  0.38268343236508978f}};
  f2 G[16];
  #pragma unroll
  for (int n0 = 0; n0 < 4; ++n0) {
    f2 a0 = y[n0], a1 = y[n0 + 4], a2 = y[n0 + 8], a3 = y[n0 + 12];
    f2 e = a0 + a2, f = a0 - a2, g = a1 + a3, h = a1 - a3;
    f2 hs = mkf2(h.y, -h.x);                     // -i*h adds as f + hs
    G[n0 * 4 + 0] = e + g;
    G[n0 * 4 + 1] = cmulc(f + hs, TX[n0][1], TY[n0][1]);
    G[n0 * 4 + 2] = cmulc(e - g, TX[n0][2], TY[n0][2]);
    G[n0 * 4 + 3] = cmulc(f - hs, TX[n0][3], TY[n0][3]);
  }
  #pragma unroll
  for (int q = 0; q < 4; ++q) {
    f2 a0 = G[q], a1 = G[4 + q], a2 = G[8 + q], a3 = G[12 + q];
    f2 e = a0 + a2, f = a0 - a2, g = a1 + a3, h = a1 - a3;
    f2 hs = mkf2(h.y, -h.x);
    y[q]      = e + g;
    y[q + 4]  = f + hs;
    y[q + 8]  = e - g;
    y[q + 12] = f - hs;
  }
}

// stage-8 butterfly for line j (natural m order), inputs gathered from LDS
__device__ __forceinline__ void bfly8(const f2* z, const f2* tst, int j, f2 X[4]) {
  f2 a  = z[SW(j)];
  f2 b_ = cmul(z[SW(j + 256)], tst[j]);
  f2 c  = cmul(z[SW(j + 512)], tst[2 * j]);
  f2 d  = cmul(z[SW(j + 768)], tst[3 * j]);
  f2 t0 = a + c, t1 = a - c, t2 = b_ + d, t3 = b_ - d;
  f2 hs = mkf2(t3.y, -t3.x);
  X[0] = t0 + t2;        // m=0
  X[1] = t1 + hs;        // m=1  (t1 - i*t3)
  X[2] = t0 - t2;        // m=2
  X[3] = t1 - hs;        // m=3  (t1 + i*t3)
}

// rFFT unpack of one (Zk, Zm) pair -> mw[k], mw[1024-k]
__device__ __forceinline__ void unpack_pair(f2 Zk, f2 Zm, f2 w, int k,
                                            ushort* __restrict__ mw) {
  const f2 Xe = (Zk + mkf2(Zm.x, -Zm.y)) * 0.5f;
  const f2 Xo = mkf2(Zk.y + Zm.y, Zm.x - Zk.x) * 0.5f;
  const f2 wXo = cmul(w, Xo);
  const f2 X = Xe + wXo;
  const f2 Y = Xe - wXo;
  mw[k]        = (ushort)bf16r(sqrtf(X.x * X.x + X.y * X.y));
  mw[1024 - k] = (ushort)bf16r(sqrtf(Y.x * Y.x + Y.y * Y.y));
}

// -------- stage 2: windowed rFFT magnitude -> bf16 MW[f][k] coalesced --------
__global__ __launch_bounds__(256)
void stft_fft(const float* __restrict__ x, const float* __restrict__ hann,
              const f2* __restrict__ Tst, const f2* __restrict__ Tun,
              ushort* __restrict__ MW)
{
  __shared__ f2 zsh[4][1024];        // per-wave z, XOR-swizzled   32768 B
  __shared__ f2 tst[1024];           // stage twiddles              8192 B  (40960 total)

  const int tid = threadIdx.x, wv = tid >> 6, lane = tid & 63;
  #pragma unroll
  for (int u = 0; u < 4; ++u) tst[u * 256 + tid] = Tst[u * 256 + tid];
  __syncthreads();                   // tables ready; the ONLY barrier

  f2* z = zsh[wv];

  // per-lane geometry
  const int G  = ((lane & 3) << 4) | (lane & 12) | (lane >> 4);  // base-4 reverse
  const int zb = 16 * G, gm = G & 15;
  const int j0 = lane & 15, B = lane >> 4;

  const int f = blockIdx.x * 4 + wv;              // 1 frame per wave, grid NFR/4
  const int b = f / TFR, t = f - b * TFR;
  const float* xb = x + (size_t)b * LSIG;
  const int off = t * HOP - 1024;

  // load f32 pairs directly, window (packed mul), stages 0+2 in regs, scatter
  f2 y[16];
  if (t >= 2 && t <= 623) {                       // interior: off>=0, off+2047<LSIG
    #pragma unroll
    for (int u = 0; u < 16; ++u) {
      const int n = u * 64 + lane;
      const f2 p = *(const f2*)(xb + off + 2 * n);
      const f2 h = *(const f2*)(hann + 2 * n);
      y[u] = p * h;
    }
  } else {                                        // boundary: per-element reflect
    #pragma unroll
    for (int u = 0; u < 16; ++u) {
      const int n = u * 64 + lane;
      int ja = off + 2 * n, jb = ja + 1;
      ja = ja < 0 ? -ja : (ja >= LSIG ? 2 * LSIG - 2 - ja : ja);
      jb = jb < 0 ? -jb : (jb >= LSIG ? 2 * LSIG - 2 - jb : jb);
      const f2 h = *(const f2*)(hann + 2 * n);
      y[u] = mkf2(xb[ja], xb[jb]) * h;
    }
  }
  fft16(y);
  #pragma unroll
  for (int k = 0; k < 16; ++k) z[zb + (k ^ gm)] = y[k];

  // stages 4+6 in registers on closed set {j0 + 16a + 64b2 + 256B} (r14 math)
  {
    f2 g[4][4];
    #pragma unroll
    for (int a = 0; a < 4; ++a)
      #pragma unroll
      for (int b2 = 0; b2 < 4; ++b2)
        g[a][b2] = z[16 * (a + 4 * b2 + 16 * B) + (j0 ^ (a + 4 * b2))];
    // stage 4 (over a): STRIDE=16 -> twiddles tst[16*j0 * {1,2,3}]
    const f2 w41 = tst[16 * j0], w42 = tst[32 * j0], w43 = tst[48 * j0];
    #pragma unroll
    for (int b2 = 0; b2 < 4; ++b2) {
      f2 a0 = g[0][b2];
      f2 a1 = cmul(g[1][b2], w41);
      f2 a2 = cmul(g[2][b2], w42);
      f2 a3 = cmul(g[3][b2], w43);
      f2 t0 = a0 + a2, t1 = a0 - a2, t2 = a1 + a3, t3 = a1 - a3;
      f2 hs = mkf2(t3.y, -t3.x);
      g[0][b2] = t0 + t2;
      g[1][b2] = t1 + hs;
      g[2][b2] = t0 - t2;
      g[3][b2] = t1 - hs;
    }
    // stage 6 (over b2): STRIDE=4 -> twiddles tst[4*(j0+16*mp) * {1,2,3}]
    #pragma unroll
    for (int mp = 0; mp < 4; ++mp) {
      const int jj = 4 * (j0 + 16 * mp);
      f2 a0 = g[mp][0];
      f2 a1 = cmul(g[mp][1], tst[jj]);
      f2 a2 = cmul(g[mp][2], tst[2 * jj]);
      f2 a3 = cmul(g[mp][3], tst[3 * jj]);
      f2 t0 = a0 + a2, t1 = a0 - a2, t2 = a1 + a3, t3 = a1 - a3;
      f2 hs = mkf2(t3.y, -t3.x);
      g[mp][0] = t0 + t2;
      g[mp][1] = t1 + hs;
      g[mp][2] = t0 - t2;
      g[mp][3] = t1 - hs;
    }
    #pragma unroll
    for (int mp = 0; mp < 4; ++mp)
      #pragma unroll
      for (int m2 = 0; m2 < 4; ++m2)
        z[16 * (mp + 4 * m2 + 16 * B) + (j0 ^ (mp + 4 * m2))] = g[mp][m2];
  }
  // z now holds Z7 (stage-6 output). Stage 8 + unpack fused below (no z writes).
  asm volatile("" ::: "memory");     // order the scatter before the gathers

  ushort* mw = MW + (size_t)f * MWS;

  // mirror-line pairs: lane handles lines j1 = u*64+lane+1 and j2 = 256-j1.
  // X[1024-(j1+256m)] = line-j2 output at 3-m (exact for j1 in 1..128;
  // j1=128 -> j2=128 self-degenerates correctly).
  #pragma unroll
  for (int u = 0; u < 2; ++u) {
    const int j1 = u * 64 + lane + 1;              // 1..128
    const int j2 = 256 - j1;                       // 255..128
    f2 Xa[4], Xb[4];
    bfly8(z, tst, j1, Xa);
    bfly8(z, tst, j2, Xb);
    #pragma unroll
    for (int m = 0; m < 2; ++m) {
      const int ka = j1 + 256 * m;                 // 1..384
      unpack_pair(Xa[m], Xb[3 - m], Tun[ka], ka, mw);
      const int kb = j2 + 256 * m;                 // 128..511
      unpack_pair(Xb[m], Xa[3 - m], Tun[kb], kb, mw);
    }
  }

  // line 0 (self-complete): slots {0,256,512,768} + Nyquist 1024
  if (lane == 0) {
    f2 X0[4];
    f2 a  = z[SW(0)];
    f2 b_ = z[SW(256)];
    f2 c  = z[SW(512)];
    f2 d  = z[SW(768)];
    f2 t0 = a + c, t1 = a - c, t2 = b_ + d, t3 = b_ - d;
    f2 hs = mkf2(t3.y, -t3.x);
    X0[0] = t0 + t2; X0[1] = t1 + hs; X0[2] = t0 - t2; X0[3] = t1 - hs;
    // k=0: Zm = Z[0] itself; writes mw[0], mw[1024]
    unpack_pair(X0[0], X0[0], Tun[0], 0, mw);      // mw[1024-0] -> mw[1024] OK
    // k=256: Zm = Z[768]
    unpack_pair(X0[1], X0[3], Tun[256], 256, mw);
    // k=512: Zm = Z[512] itself; |X| == |Z[512]| (mw[512] double-write benign)
    unpack_pair(X0[2], X0[2], Tun[512], 512, mw);
  }
}

// -------- stage 3: transpose [f][k] bf16 -> out[b][k][t] f32 (r9-proven) --------
__global__ __launch_bounds__(256)
void transpose_out(const ushort* __restrict__ MW, float* __restrict__ out) {
  __shared__ float tile[64][33];
  const int b  = blockIdx.y;
  const int kt = blockIdx.x % KT;
  const int tt = blockIdx.x / KT;
  const int k0 = kt * 64, t0 = tt * 32;
  const int tid = threadIdx.x;
  const int r = tid >> 5, c = tid & 31;

  #pragma unroll
  for (int s = 0; s < 4; ++s) {
    const int t = t0 + r + 8 * s;
    if (t < TFR) {
      const uint32_t pr =
        *(const uint32_t*)(MW + (size_t)(b * TFR + t) * MWS + k0 + 2 * c);
      tile[2 * c][r + 8 * s]     = bf2f(pr & 0xffffu);
      tile[2 * c + 1][r + 8 * s] = bf2f(pr >> 16);
    }
  }
  __syncthreads();

  const int kk = tid >> 2, toff = (tid & 3) * 8;
  const int k = k0 + kk;
  if (k < CUT) {
    float* pptr = out + (size_t)b * (CUT * TFR) + (size_t)k * TFR + t0 + toff;
    if (t0 + 32 <= TFR) {
      float4 v0 = make_float4(tile[kk][toff], tile[kk][toff + 1],
                              tile[kk][toff + 2], tile[kk][toff + 3]);
      float4 v1 = make_float4(tile[kk][toff + 4], tile[kk][toff + 5],
                              tile[kk][toff + 6], tile[kk][toff + 7]);
      *(float4*)pptr = v0;
      *(float4*)(pptr + 4) = v1;
    } else {
      #pragma unroll
      for (int e = 0; e < 8; ++e) {
        const int t = t0 + toff + e;
        if (t < TFR) pptr[e] = tile[kk][toff + e];
      }
    }
  }
}

// -------- fallback: reg-staged 128x128 MFMA GEMM (no ws needed) --------
typedef __attribute__((ext_vector_type(4))) float f32x4;

__global__ __launch_bounds__(256, 2)
void stft_gemm_fb(const float* __restrict__ basis, const float* __restrict__ x,
                  float* __restrict__ out)
{
  __shared__ alignas(16) short sA[2][128][64];
  __shared__ alignas(16) short sB[128][64];

  const int tid  = threadIdx.x;
  const int wave = tid >> 6;
  const int lane = tid & 63;
  const int n0 = blockIdx.x * 128;
  const int m0 = blockIdx.y * 128;

  f32x4 acc_r[4][4], acc_i[4][4];
  #pragma unroll
  for (int i = 0; i < 4; ++i)
    #pragma unroll
    for (int j = 0; j < 4; ++j) { acc_r[i][j] = (f32x4)0.f; acc_i[i][j] = (f32x4)0.f; }

  const int sr = tid >> 1;
  const int sh = (tid & 1) * 32;

  for (int k0 = 0; k0 < FILT; k0 += 64) {
    #pragma unroll
    for (int p = 0; p < 2; ++p) {
      const int k = m0 + sr;
      short8 v[4];
      if (k < CUT) {
        const float* src = basis + (size_t)(p * CUT + k) * FILT + k0 + sh;
        #pragma unroll
        for (int qq = 0; qq < 4; ++qq) {
          float4 a = *(const float4*)(src + qq * 8);
          float4 b = *(const float4*)(src + qq * 8 + 4);
          v[qq] = pack8(a, b);
        }
      } else {
        #pragma unroll
        for (int qq = 0; qq < 4; ++qq) v[qq] = (short8)(short)0;
      }
      #pragma unroll
      for (int qq = 0; qq < 4; ++qq) *(short8*)&sA[p][sr][sh + qq * 8] = v[qq];
    }
    {
      const int f = n0 + sr;
      short8 v[4];
      if (f < NFR) {
        const int b = f / TFR, t = f - b * TFR;
        const float* xb = x + (size_t)b * LSIG;
        const int j0 = t * HOP + k0 + sh - 1024;
        if (j0 >= 0 && j0 + 32 <= LSIG) {
          #pragma unroll
          for (int qq = 0; qq < 4; ++qq) {
            float4 a  = *(const float4*)(xb + j0 + qq * 8);
            float4 b2 = *(const float4*)(xb + j0 + qq * 8 + 4);
            v[qq] = pack8(a, b2);
          }
        } else {
          #pragma unroll
          for (int qq = 0; qq < 4; ++qq)
            #pragma unroll
            for (int e = 0; e < 8; ++e) {
              int j = j0 + qq * 8 + e;
              j = j < 0 ? -j : (j >= LSIG ? 2 * LSIG - 2 - j : j);
              v[qq][e] = bf16r(xb[j]);
            }
        }
      } else {
        #pragma unroll
        for (int qq = 0; qq < 4; ++qq) v[qq] = (short8)(short)0;
      }
      #pragma unroll
      for (int qq = 0; qq < 4; ++qq) *(short8*)&sB[sr][sh + qq * 8] = v[qq];
    }
    __syncthreads();

    const int ra = lane & 15;
    #pragma unroll
    for (int kk = 0; kk < 64; kk += 32) {
      const int col = kk + (lane >> 4) * 8;
      short8 arr[4], aii[4], bfr[4];
      #pragma unroll
      for (int i = 0; i < 4; ++i) {
        const int rm = (wave >> 1) * 64 + i * 16 + ra;
        arr[i] = *(const short8*)&sA[0][rm][col];
        aii[i] = *(const short8*)&sA[1][rm][col];
        const int rn = (wave & 1) * 64 + i * 16 + ra;
        bfr[i] = *(const short8*)&sB[rn][col];
      }
      #pragma unroll
      for (int i = 0; i < 4; ++i)
        #pragma unroll
        for (int j = 0; j < 4; ++j) {
          acc_r[i][j] = __builtin_amdgcn_mfma_f32_16x16x32_bf16(arr[i], bfr[j], acc_r[i][j], 0, 0, 0);
          acc_i[i][j] = __builtin_amdgcn_mfma_f32_16x16x32_bf16(aii[i], bfr[j], acc_i[i][j], 0, 0, 0);
        }
    }
    __syncthreads();
  }

  const int wm0 = m0 + (wave >> 1) * 64;
  const int wn0 = n0 + (wave & 1) * 64;
  const int cl = lane & 15;
  const int rg = (lane >> 4) * 4;
  #pragma unroll
  for (int j = 0; j < 4; ++j) {
    const int f = wn0 + j * 16 + cl;
    if (f >= NFR) continue;
    const int b = f / TFR, t = f - b * TFR;
    float* ob = out + (size_t)b * (CUT * TFR) + t;
    #pragma unroll
    for (int i = 0; i < 4; ++i) {
      #pragma unroll
      for (int r = 0; r < 4; ++r) {
        const int k = wm0 + i * 16 + rg + r;
        if (k < CUT) {
          float re = acc_r[i][j][r], im = acc_i[i][j][r];
          ob[(size_t)k * TFR] = sqrtf(re * re + im * im);
        }
      }
    }
  }
}

extern "C" void kernel_launch(void* const* d_in, const int* in_sizes, int n_in,
                              void* d_out, int out_size, void* d_ws, size_t ws_size,
                              hipStream_t stream) {
  const float* x     = (const float*)d_in[0];
  const float* basis = (const float*)d_in[1];
  float* out = (float*)d_out;

  const size_t hbytes = 2048 * sizeof(float);                    // 8 KB
  const size_t tbytes = 1024 * sizeof(float2);                   // 8 KB each
  const size_t mbytes = (size_t)NFR * MWS * sizeof(ushort);      // 43,589,632

  if (ws_size >= hbytes + 2 * tbytes + mbytes) {
    float*  hann = (float*)d_ws;
    float2* Tst  = (float2*)((char*)d_ws + hbytes);
    float2* Tun  = (float2*)((char*)d_ws + hbytes + tbytes);
    ushort* MW   = (ushort*)((char*)d_ws + hbytes + 2 * tbytes);
    make_tables<<<8, 256, 0, stream>>>(hann, Tst, Tun);
    stft_fft<<<NFR / 4, 256, 0, stream>>>(x, hann, (const f2*)Tst, (const f2*)Tun, MW);
    transpose_out<<<dim3(KT * TT, NBATCH), 256, 0, stream>>>(MW, out);
  } else {
    stft_gemm_fb<<<dim3(157, 9), 256, 0, stream>>>(basis, x, out);
  }
}